// Round 5
// baseline (2342.637 us; speedup 1.0000x reference)
//
#include <hip/hip_runtime.h>
#include <hip/hip_bf16.h>
#include <cstdint>

// Problem constants: B=64, T=512, E=256, H=128, 4H=512.
#define BB 64
#define TT 512
#define EE 256
#define HH 128
#define G4 512

typedef _Float16 f16x4 __attribute__((ext_vector_type(4)));
typedef _Float16 f16x8 __attribute__((ext_vector_type(8)));
typedef float f32x4 __attribute__((ext_vector_type(4)));

__device__ __forceinline__ float rcp_(float x) { return __builtin_amdgcn_rcpf(x); }
__device__ __forceinline__ float sigmoid_(float x) { return rcp_(1.f + __expf(-x)); }
__device__ __forceinline__ float tanh_(float x) {
  float ax = fabsf(x);
  float e = __expf(-2.f * ax);  // in (0,1], no overflow
  float r = (1.f - e) * rcp_(1.f + e);
  return copysignf(r, x);
}
// DPP-based wave reduction (VALU pipe, NOT the LDS pipe like __shfl).
template <int ctrl>
__device__ __forceinline__ float dpp_add(float x) {
  int y = __builtin_amdgcn_update_dpp(0, __builtin_bit_cast(int, x), ctrl, 0xf, 0xf, true);
  return x + __builtin_bit_cast(float, y);
}
__device__ __forceinline__ float wave_sum63(float x) {  // total lands in lane 63
  x = dpp_add<0x111>(x);  // row_shr:1
  x = dpp_add<0x112>(x);  // row_shr:2
  x = dpp_add<0x114>(x);  // row_shr:4
  x = dpp_add<0x118>(x);  // row_shr:8
  x = dpp_add<0x142>(x);  // row_bcast:15
  x = dpp_add<0x143>(x);  // row_bcast:31
  return x;
}
__device__ __forceinline__ float sel4(f32x4 v, int s) {  // v[s], s in [0,4)
  float a = (s & 1) ? v[1] : v[0];
  float b = (s & 1) ? v[3] : v[2];
  return (s & 2) ? b : a;
}

// ---------------------------------------------------------------------------
// Kernel A: trans = row-softmax(transition); W16 = (f16)W_ih; Whh16 = (f16)W_hh
// grid 320 x 128 threads.
// ---------------------------------------------------------------------------
__global__ __launch_bounds__(128) void prep_kernel(
    const float* __restrict__ transition, const float* __restrict__ W_ih,
    const float* __restrict__ W_hh, float* __restrict__ trans,
    _Float16* __restrict__ W16, _Float16* __restrict__ Whh16) {
  const int bid = blockIdx.x, t = threadIdx.x;
  if (bid < 128) {
    __shared__ float red[2];
    float v = transition[bid * HH + t];
    float m = v;
#pragma unroll
    for (int s = 32; s >= 1; s >>= 1) m = fmaxf(m, __shfl_xor(m, s));
    if ((t & 63) == 0) red[t >> 6] = m;
    __syncthreads();
    m = fmaxf(red[0], red[1]);
    float e = __expf(v - m);
    float s = e;
#pragma unroll
    for (int k = 32; k >= 1; k >>= 1) s += __shfl_xor(s, k);
    __syncthreads();
    if ((t & 63) == 0) red[t >> 6] = s;
    __syncthreads();
    trans[bid * HH + t] = e * rcp_(red[0] + red[1]);
  } else if (bid < 256) {
    const int base = (bid - 128) * 1024 + t * 8;  // 131072 elems of W_ih
    float4 v0 = *(const float4*)(W_ih + base);
    float4 v1 = *(const float4*)(W_ih + base + 4);
    f16x8 h;
    h[0] = (_Float16)v0.x; h[1] = (_Float16)v0.y;
    h[2] = (_Float16)v0.z; h[3] = (_Float16)v0.w;
    h[4] = (_Float16)v1.x; h[5] = (_Float16)v1.y;
    h[6] = (_Float16)v1.z; h[7] = (_Float16)v1.w;
    *(f16x8*)(W16 + base) = h;
  } else {
    const int base = (bid - 256) * 1024 + t * 8;  // 65536 elems of W_hh
    float4 v0 = *(const float4*)(W_hh + base);
    float4 v1 = *(const float4*)(W_hh + base + 4);
    f16x8 h;
    h[0] = (_Float16)v0.x; h[1] = (_Float16)v0.y;
    h[2] = (_Float16)v0.z; h[3] = (_Float16)v0.w;
    h[4] = (_Float16)v1.x; h[5] = (_Float16)v1.y;
    h[6] = (_Float16)v1.z; h[7] = (_Float16)v1.w;
    *(f16x8*)(Whh16 + base) = h;
  }
}

// ---------------------------------------------------------------------------
// Kernel A2: ETT[j][i] = (f16) exp(trans[i][j])  (transposed exp-transition)
// ---------------------------------------------------------------------------
__global__ __launch_bounds__(256) void prep2_kernel(
    const float* __restrict__ trans, _Float16* __restrict__ ETT) {
  const int idx = blockIdx.x * 256 + threadIdx.x;  // 16384 total
  const int j = idx >> 7, i = idx & 127;
  ETT[j * HH + i] = (_Float16)__expf(trans[i * HH + j]);
}

// ---------------------------------------------------------------------------
// Kernel B: precomp[m][j] = inputs@W_ih^T + b_ih + b_hh (f16 MFMA 16x16x32)
// ---------------------------------------------------------------------------
__global__ __launch_bounds__(256) void gemm_in(
    const float* __restrict__ A, const _Float16* __restrict__ W16,
    const float* __restrict__ b_ih, const float* __restrict__ b_hh,
    float* __restrict__ out) {
  __shared__ _Float16 As[64][264];
  const int t = threadIdx.x;
  const int m0 = blockIdx.x * 64;
  const int n0 = blockIdx.y * 256;
  {
    const int c4 = t & 63, r0 = t >> 6;
#pragma unroll
    for (int p = 0; p < 16; ++p) {
      const int row = r0 + 4 * p;
      float4 v = *(const float4*)(A + (size_t)(m0 + row) * EE + c4 * 4);
      f16x4 h;
      h[0] = (_Float16)v.x; h[1] = (_Float16)v.y;
      h[2] = (_Float16)v.z; h[3] = (_Float16)v.w;
      *(f16x4*)&As[row][c4 * 4] = h;
    }
  }
  __syncthreads();
  const int w = t >> 6, L = t & 63;
  const int lrow = L & 15, quad = L >> 4, lk = quad * 8;
  f32x4 acc[4][4] = {};
  const _Float16* Wbase = W16 + (size_t)(n0 + w * 64) * EE;
#pragma unroll
  for (int kc = 0; kc < 8; ++kc) {
    f16x8 a[4], bf[4];
#pragma unroll
    for (int mf = 0; mf < 4; ++mf)
      a[mf] = *(const f16x8*)&As[mf * 16 + lrow][kc * 32 + lk];
#pragma unroll
    for (int nf = 0; nf < 4; ++nf)
      bf[nf] = *(const f16x8*)(Wbase + (size_t)(nf * 16 + lrow) * EE + kc * 32 + lk);
#pragma unroll
    for (int mf = 0; mf < 4; ++mf)
#pragma unroll
      for (int nf = 0; nf < 4; ++nf)
        acc[mf][nf] = __builtin_amdgcn_mfma_f32_16x16x32_f16(a[mf], bf[nf], acc[mf][nf], 0, 0, 0);
  }
#pragma unroll
  for (int nf = 0; nf < 4; ++nf) {
    const int jj = n0 + w * 64 + nf * 16 + lrow;
    const float bias = b_ih[jj] + b_hh[jj];
#pragma unroll
    for (int mf = 0; mf < 4; ++mf) {
#pragma unroll
      for (int r = 0; r < 4; ++r) {
        const int m = m0 + mf * 16 + quad * 4 + r;
        out[(size_t)m * G4 + jj] = acc[mf][nf][r] + bias;
      }
    }
  }
}

// ---------------------------------------------------------------------------
// Kernel C: fused LSTM + softmax + CRF forward, WAVE-SPECIALIZED.
// 512 thr = 8 waves (2/SIMD: one LSTM wave + one CRF wave per SIMD).
// Waves 0-3 (LSTM): wave ww owns units 32ww..32ww+31, all 4 gates =
//   8 row-tiles x 4 kc = 32 MFMA 16x16x32; A-frags (W_hh f16) in 128 VGPRs.
// Waves 4-7 (CRF): wave ww owns CRF cols 32ww..32ww+31 = 2 tiles x 4 kc =
//   8 MFMA; A-frags (exp(trans)^T) in 32 VGPRs.  CRF lags LSTM by 1 iter.
// Lane (quad,col): A-row = col; lane processes unit
//   ju = 32ww + (col&7)>>2 *16 + quad*4 + (col&3); cols 8-15 duplicate,
//   masked out of reductions/writes (wr = col<8) -> exact sums.
// One barrier/step; h16/E16/redE/pre0 double-buffered across it.
// ---------------------------------------------------------------------------
__global__ __launch_bounds__(512, 2) void lstm_crf(
    const float* __restrict__ precomp, const _Float16* __restrict__ Whh16,
    const _Float16* __restrict__ ETT, const float* __restrict__ trans,
    const int* __restrict__ labels, float* __restrict__ out_b) {
  const int b = blockIdx.x, t = threadIdx.x;
  const int w = t >> 6, L = t & 63;
  const int quad = L >> 4, col = L & 15;
  const int cu = col & 7, utile = cu >> 2, r4 = cu & 3;
  const bool isL = (w < 4);
  const int ww = isL ? w : (w - 4);
  const int ju = 32 * ww + utile * 16 + quad * 4 + r4;  // owned unit / CRF col
  const bool wr = (col < 8);                            // distinct-unit lanes

  __shared__ __align__(16) _Float16 h16[2][HH];
  __shared__ __align__(16) _Float16 E16[2][HH];
  __shared__ __align__(16) float redE[2][4];
  __shared__ float pre0[2];
  __shared__ float fin[12];
  __shared__ int lab[TT];

  // ---- one-time A-fragment loads ------------------------------------------
  f16x8 Al[8][4];  // LSTM [tile=g*2+u][kc]
  f16x8 Ac[2][4];  // CRF
  float tr0 = 0.f, tr127 = 0.f;
  if (isL) {
#pragma unroll
    for (int g = 0; g < 4; ++g)
#pragma unroll
      for (int u = 0; u < 2; ++u) {
        const int row = g * 128 + 32 * ww + u * 16 + col;  // A-row = col
#pragma unroll
        for (int kc = 0; kc < 4; ++kc)
          Al[g * 2 + u][kc] = *(const f16x8*)(Whh16 + row * HH + kc * 32 + quad * 8);
      }
  } else {
#pragma unroll
    for (int u = 0; u < 2; ++u) {
      const int row = 32 * ww + u * 16 + col;
#pragma unroll
      for (int kc = 0; kc < 4; ++kc)
        Ac[u][kc] = *(const f16x8*)(ETT + row * HH + kc * 32 + quad * 8);
    }
    tr0 = trans[ju];
    tr127 = trans[127 * HH + ju];
  }
  lab[t] = labels[b * TT + t];
  if (t < HH) {
    h16[0][t] = (_Float16)0.f; h16[1][t] = (_Float16)0.f;
    E16[0][t] = (_Float16)0.f; E16[1][t] = (_Float16)0.f;
  }
  if (t < 8) redE[t >> 2][t & 3] = 0.f;
  if (t < 2) pre0[t] = 0.f;

  const float* pcb = precomp + (size_t)b * TT * G4;
  float4 nxt[8];
  if (isL) {
#pragma unroll
    for (int g = 0; g < 4; ++g)
#pragma unroll
      for (int u = 0; u < 2; ++u)
        nxt[g * 2 + u] = *(const float4*)(pcb + g * 128 + 32 * ww + u * 16 + quad * 4);
  }
  float cst = 0.f, pre = 0.f, mused = 0.f, emit = 0.f;
  __syncthreads();

#pragma unroll 1
  for (int n = 0; n <= TT; ++n) {
    if (isL) {
      if (n < TT) {
        // B-frag: h(n-1) broadcast (value independent of col)
        const _Float16* hb = &h16[(n + 1) & 1][0];
        f16x8 Bh[4];
#pragma unroll
        for (int kc = 0; kc < 4; ++kc)
          Bh[kc] = *(const f16x8*)(hb + kc * 32 + quad * 8);
        f32x4 acc[8];
#pragma unroll
        for (int i = 0; i < 8; ++i) acc[i] = __builtin_bit_cast(f32x4, nxt[i]);
#pragma unroll
        for (int kc = 0; kc < 4; ++kc)
#pragma unroll
          for (int i = 0; i < 8; ++i)
            acc[i] = __builtin_amdgcn_mfma_f32_16x16x32_f16(Al[i][kc], Bh[kc], acc[i], 0, 0, 0);
        // prefetch next step's precomp (after acc consumed nxt)
        if (n + 1 < TT) {
          const float* p2 = pcb + (size_t)(n + 1) * G4;
#pragma unroll
          for (int g = 0; g < 4; ++g)
#pragma unroll
            for (int u = 0; u < 2; ++u)
              nxt[g * 2 + u] = *(const float4*)(p2 + g * 128 + 32 * ww + u * 16 + quad * 4);
        }
        // activations for my unit ju (gate g in acc[g*2+utile], element r4)
        const float gi = sel4(acc[0 + utile], r4);
        const float gf = sel4(acc[2 + utile], r4);
        const float gg = sel4(acc[4 + utile], r4);
        const float go = sel4(acc[6 + utile], r4);
        cst = sigmoid_(gf) * cst + sigmoid_(gi) * tanh_(gg);
        const float hv = sigmoid_(go) * tanh_(cst);
        const float e = wr ? __expf(hv) : 0.f;  // |hv|<1
        float ts = wave_sum63(e);               // exact 32-unit sum
        if (L == 63) redE[n & 1][ww] = ts;
        if (wr) h16[n & 1][ju] = (_Float16)hv;
      }
    } else {
      if (n > 0) {
        // B-frag: E(n-2)
        const _Float16* eb = &E16[n & 1][0];
        f16x8 Be[4];
#pragma unroll
        for (int kc = 0; kc < 4; ++kc)
          Be[kc] = *(const f16x8*)(eb + kc * 32 + quad * 8);
        f32x4 s0 = {0.f, 0.f, 0.f, 0.f}, s1 = {0.f, 0.f, 0.f, 0.f};
#pragma unroll
        for (int kc = 0; kc < 4; ++kc) {
          s0 = __builtin_amdgcn_mfma_f32_16x16x32_f16(Ac[0][kc], Be[kc], s0, 0, 0, 0);
          s1 = __builtin_amdgcn_mfma_f32_16x16x32_f16(Ac[1][kc], Be[kc], s1, 0, 0, 0);
        }
        const float4 rE = *(const float4*)&redE[(n + 1) & 1][0];  // tot(n-1)
        float Mnew = pre0[(n + 1) & 1];                           // pre(n-2)[0]
        const int labn = lab[n - 1];
        const float hj = (float)h16[(n + 1) & 1][ju];  // h(n-1) of my unit
        const float ej = __expf(hj);
        const float tot = rE.x + rE.y + rE.z + rE.w;   // exact sum of e's
        const float p = ej * rcp_(tot);                // softmax prob of ju
        const float S = utile ? sel4(s1, r4) : sel4(s0, r4);
        if (n == 1) { pre = p + tr0; Mnew = 0.f; }
        else pre = p + mused + __logf(S);
        if (t == 256) pre0[n & 1] = pre;  // wave 4 lane 0 owns unit 0
        if (wr) E16[(n + 1) & 1][ju] = (_Float16)__expf(pre - Mnew);
        mused = Mnew;
        if (wr && labn == ju) emit += p;
      }
    }
    __syncthreads();
  }

  // ---- epilogue: Ps = LSE_j(pre + trans[127][j]); out_b = Ps - emit -------
  float v = 0.f, mx = -1e30f;
  if (!isL) { v = pre + tr127; mx = v; }
#pragma unroll
  for (int d = 1; d <= 32; d <<= 1) mx = fmaxf(mx, __shfl_xor(mx, d));
  if (!isL && L == 0) fin[ww] = mx;
  __syncthreads();
  if (!isL) {
    const float M2 = fmaxf(fmaxf(fin[0], fin[1]), fmaxf(fin[2], fin[3]));
    float ex = wave_sum63(wr ? __expf(v - M2) : 0.f);
    float em = wave_sum63(wr ? emit : 0.f);
    if (L == 63) { fin[4 + ww] = ex; fin[8 + ww] = em; }
  }
  __syncthreads();
  if (t == 256) {
    const float M2 = fmaxf(fmaxf(fin[0], fin[1]), fmaxf(fin[2], fin[3]));
    float S = 0.f, E = 0.f;
#pragma unroll
    for (int i = 0; i < 4; ++i) { S += fin[4 + i]; E += fin[8 + i]; }
    out_b[b] = (M2 + __logf(S)) - E;
  }
}

// ---------------------------------------------------------------------------
// Kernel D: d_out += out_b[b] - sum_t trans[l_t][l_{t+1}]   (one block per b)
// ---------------------------------------------------------------------------
__global__ __launch_bounds__(256) void finalize_kernel(
    const float* __restrict__ trans, const int* __restrict__ labels,
    const float* __restrict__ out_b, float* __restrict__ d_out) {
  const int b = blockIdx.x, t = threadIdx.x;
  float a = 0.f;
  for (int i = t; i < TT - 1; i += 256) {
    const int l0 = labels[b * TT + i];
    const int l1 = labels[b * TT + i + 1];
    a += trans[l0 * HH + l1];
  }
#pragma unroll
  for (int d = 1; d <= 32; d <<= 1) a += __shfl_xor(a, d);
  __shared__ float red[4];
  if ((t & 63) == 0) red[t >> 6] = a;
  __syncthreads();
  if (t == 0) {
    const float tr = red[0] + red[1] + red[2] + red[3];
    atomicAdd(d_out, out_b[b] - tr);
  }
}

// ---------------------------------------------------------------------------
extern "C" void kernel_launch(void* const* d_in, const int* in_sizes, int n_in,
                              void* d_out, int out_size, void* d_ws, size_t ws_size,
                              hipStream_t stream) {
  const float* inputs = (const float*)d_in[0];
  const int* labels = (const int*)d_in[1];
  const float* W_ih = (const float*)d_in[2];
  const float* W_hh = (const float*)d_in[3];
  const float* b_ih = (const float*)d_in[4];
  const float* b_hh = (const float*)d_in[5];
  const float* transition = (const float*)d_in[6];

  char* ws = (char*)d_ws;
  float* precomp = (float*)ws;                              // 64 MiB
  size_t off = 67108864;
  float* trans = (float*)(ws + off); off += 65536;          // 64 KiB
  _Float16* W16 = (_Float16*)(ws + off); off += 262144;     // 256 KiB
  _Float16* Whh16 = (_Float16*)(ws + off); off += 131072;   // 128 KiB
  _Float16* ETT = (_Float16*)(ws + off); off += 32768;      // 32 KiB
  float* out_b = (float*)(ws + off);

  prep_kernel<<<320, 128, 0, stream>>>(transition, W_ih, W_hh, trans, W16, Whh16);
  prep2_kernel<<<64, 256, 0, stream>>>(trans, ETT);
  gemm_in<<<dim3(512, 2), 256, 0, stream>>>(inputs, W16, b_ih, b_hh, precomp);
  lstm_crf<<<64, 512, 0, stream>>>(precomp, Whh16, ETT, trans, labels, out_b);
  (void)hipMemsetAsync(d_out, 0, sizeof(float), stream);
  finalize_kernel<<<64, 256, 0, stream>>>(trans, labels, out_b, (float*)d_out);
}

// Round 6
// 963.910 us; speedup vs baseline: 2.4303x; 2.4303x over previous
//
#include <hip/hip_runtime.h>
#include <hip/hip_bf16.h>
#include <cstdint>

// Problem constants: B=64, T=512, E=256, H=128, 4H=512.
#define BB 64
#define TT 512
#define EE 256
#define HH 128
#define G4 512

typedef _Float16 f16x4 __attribute__((ext_vector_type(4)));
typedef _Float16 f16x8 __attribute__((ext_vector_type(8)));
typedef float f32x4 __attribute__((ext_vector_type(4)));

__device__ __forceinline__ float rcp_(float x) { return __builtin_amdgcn_rcpf(x); }
__device__ __forceinline__ float sigmoid_(float x) { return rcp_(1.f + __expf(-x)); }
__device__ __forceinline__ float tanh_(float x) {
  float ax = fabsf(x);
  float e = __expf(-2.f * ax);  // in (0,1], no overflow
  float r = (1.f - e) * rcp_(1.f + e);
  return copysignf(r, x);
}
// DPP-based wave reduction (VALU pipe, NOT the LDS pipe like __shfl).
template <int ctrl>
__device__ __forceinline__ float dpp_add(float x) {
  int y = __builtin_amdgcn_update_dpp(0, __builtin_bit_cast(int, x), ctrl, 0xf, 0xf, true);
  return x + __builtin_bit_cast(float, y);
}
__device__ __forceinline__ float wave_sum63(float x) {  // total lands in lane 63
  x = dpp_add<0x111>(x);  // row_shr:1
  x = dpp_add<0x112>(x);  // row_shr:2
  x = dpp_add<0x114>(x);  // row_shr:4
  x = dpp_add<0x118>(x);  // row_shr:8
  x = dpp_add<0x142>(x);  // row_bcast:15
  x = dpp_add<0x143>(x);  // row_bcast:31
  return x;
}

// ---------------------------------------------------------------------------
// Kernel A: trans = row-softmax(transition); W16 = (f16)W_ih; Whh16 = (f16)W_hh
// grid 320 x 128 threads.
// ---------------------------------------------------------------------------
__global__ __launch_bounds__(128) void prep_kernel(
    const float* __restrict__ transition, const float* __restrict__ W_ih,
    const float* __restrict__ W_hh, float* __restrict__ trans,
    _Float16* __restrict__ W16, _Float16* __restrict__ Whh16) {
  const int bid = blockIdx.x, t = threadIdx.x;
  if (bid < 128) {
    __shared__ float red[2];
    float v = transition[bid * HH + t];
    float m = v;
#pragma unroll
    for (int s = 32; s >= 1; s >>= 1) m = fmaxf(m, __shfl_xor(m, s));
    if ((t & 63) == 0) red[t >> 6] = m;
    __syncthreads();
    m = fmaxf(red[0], red[1]);
    float e = __expf(v - m);
    float s = e;
#pragma unroll
    for (int k = 32; k >= 1; k >>= 1) s += __shfl_xor(s, k);
    __syncthreads();
    if ((t & 63) == 0) red[t >> 6] = s;
    __syncthreads();
    trans[bid * HH + t] = e * rcp_(red[0] + red[1]);
  } else if (bid < 256) {
    const int base = (bid - 128) * 1024 + t * 8;  // 131072 elems of W_ih
    float4 v0 = *(const float4*)(W_ih + base);
    float4 v1 = *(const float4*)(W_ih + base + 4);
    f16x8 h;
    h[0] = (_Float16)v0.x; h[1] = (_Float16)v0.y;
    h[2] = (_Float16)v0.z; h[3] = (_Float16)v0.w;
    h[4] = (_Float16)v1.x; h[5] = (_Float16)v1.y;
    h[6] = (_Float16)v1.z; h[7] = (_Float16)v1.w;
    *(f16x8*)(W16 + base) = h;
  } else {
    const int base = (bid - 256) * 1024 + t * 8;  // 65536 elems of W_hh
    float4 v0 = *(const float4*)(W_hh + base);
    float4 v1 = *(const float4*)(W_hh + base + 4);
    f16x8 h;
    h[0] = (_Float16)v0.x; h[1] = (_Float16)v0.y;
    h[2] = (_Float16)v0.z; h[3] = (_Float16)v0.w;
    h[4] = (_Float16)v1.x; h[5] = (_Float16)v1.y;
    h[6] = (_Float16)v1.z; h[7] = (_Float16)v1.w;
    *(f16x8*)(Whh16 + base) = h;
  }
}

// ---------------------------------------------------------------------------
// Kernel A2: ETT[j][i] = (f16) exp(trans[i][j])  (transposed exp-transition)
// ---------------------------------------------------------------------------
__global__ __launch_bounds__(256) void prep2_kernel(
    const float* __restrict__ trans, _Float16* __restrict__ ETT) {
  const int idx = blockIdx.x * 256 + threadIdx.x;  // 16384 total
  const int j = idx >> 7, i = idx & 127;
  ETT[j * HH + i] = (_Float16)__expf(trans[i * HH + j]);
}

// ---------------------------------------------------------------------------
// Kernel B: precomp[m][j] = inputs@W_ih^T + b_ih + b_hh (f16 MFMA 16x16x32)
// ---------------------------------------------------------------------------
__global__ __launch_bounds__(256) void gemm_in(
    const float* __restrict__ A, const _Float16* __restrict__ W16,
    const float* __restrict__ b_ih, const float* __restrict__ b_hh,
    float* __restrict__ out) {
  __shared__ _Float16 As[64][264];
  const int t = threadIdx.x;
  const int m0 = blockIdx.x * 64;
  const int n0 = blockIdx.y * 256;
  {
    const int c4 = t & 63, r0 = t >> 6;
#pragma unroll
    for (int p = 0; p < 16; ++p) {
      const int row = r0 + 4 * p;
      float4 v = *(const float4*)(A + (size_t)(m0 + row) * EE + c4 * 4);
      f16x4 h;
      h[0] = (_Float16)v.x; h[1] = (_Float16)v.y;
      h[2] = (_Float16)v.z; h[3] = (_Float16)v.w;
      *(f16x4*)&As[row][c4 * 4] = h;
    }
  }
  __syncthreads();
  const int w = t >> 6, L = t & 63;
  const int lrow = L & 15, quad = L >> 4, lk = quad * 8;
  f32x4 acc[4][4] = {};
  const _Float16* Wbase = W16 + (size_t)(n0 + w * 64) * EE;
#pragma unroll
  for (int kc = 0; kc < 8; ++kc) {
    f16x8 a[4], bf[4];
#pragma unroll
    for (int mf = 0; mf < 4; ++mf)
      a[mf] = *(const f16x8*)&As[mf * 16 + lrow][kc * 32 + lk];
#pragma unroll
    for (int nf = 0; nf < 4; ++nf)
      bf[nf] = *(const f16x8*)(Wbase + (size_t)(nf * 16 + lrow) * EE + kc * 32 + lk);
#pragma unroll
    for (int mf = 0; mf < 4; ++mf)
#pragma unroll
      for (int nf = 0; nf < 4; ++nf)
        acc[mf][nf] = __builtin_amdgcn_mfma_f32_16x16x32_f16(a[mf], bf[nf], acc[mf][nf], 0, 0, 0);
  }
#pragma unroll
  for (int nf = 0; nf < 4; ++nf) {
    const int jj = n0 + w * 64 + nf * 16 + lrow;
    const float bias = b_ih[jj] + b_hh[jj];
#pragma unroll
    for (int mf = 0; mf < 4; ++mf) {
#pragma unroll
      for (int r = 0; r < 4; ++r) {
        const int m = m0 + mf * 16 + quad * 4 + r;
        out[(size_t)m * G4 + jj] = acc[mf][nf][r] + bias;
      }
    }
  }
}

// ---------------------------------------------------------------------------
// Kernel C: fused LSTM + softmax + CRF forward, SYMMETRIC 8-wave split.
// 512 thr = 8 waves (2/SIMD for latency hiding).  Wave ww owns units
// 16ww..16ww+15: 4 LSTM gate-tiles (A-frags 64 VGPR) + 1 CRF tile (16 VGPR).
// Lane (quad,col): D rows quad*4+r -> units ju0+r, ju0 = 16ww+quad*4;
// 16 cols duplicate (writers: col==0).  A wave's CRF cols == its LSTM units
// with the same lane mapping, so exp(h) for softmax stays in-register
// (e_prev) across the 1-step CRF lag.  One barrier/step; h16/E16/redE/pre0
// double-buffered.  Reductions via DPP (VALU pipe).
// ---------------------------------------------------------------------------
__global__ __launch_bounds__(512, 2) void lstm_crf(
    const float* __restrict__ precomp, const _Float16* __restrict__ Whh16,
    const _Float16* __restrict__ ETT, const float* __restrict__ trans,
    const int* __restrict__ labels, float* __restrict__ out_b) {
  const int b = blockIdx.x, t = threadIdx.x;
  const int ww = t >> 6, L = t & 63;
  const int quad = L >> 4, col = L & 15;
  const int ju0 = 16 * ww + quad * 4;  // first of my 4 units / CRF cols
  const bool wr = (col == 0);          // unique-writer lanes

  __shared__ __align__(16) _Float16 h16[2][HH];
  __shared__ __align__(16) _Float16 E16[2][HH];
  __shared__ __align__(16) float redE[2][8];
  __shared__ float pre0[2];
  __shared__ float fin[24];
  __shared__ int lab[TT];

  // ---- one-time A-fragment loads (persist in regs for all 512 steps) ------
  f16x8 Al[4][4];  // LSTM [gate][kc]; A-row-in-tile = col
#pragma unroll
  for (int g = 0; g < 4; ++g) {
    const int row = g * 128 + 16 * ww + col;
#pragma unroll
    for (int kc = 0; kc < 4; ++kc)
      Al[g][kc] = *(const f16x8*)(Whh16 + row * HH + kc * 32 + quad * 8);
  }
  f16x8 Ac[4];  // CRF tile [kc]
  {
    const int row = 16 * ww + col;
#pragma unroll
    for (int kc = 0; kc < 4; ++kc)
      Ac[kc] = *(const f16x8*)(ETT + row * HH + kc * 32 + quad * 8);
  }
  const float4 tr0 = *(const float4*)(trans + ju0);
  const float4 tr127 = *(const float4*)(trans + 127 * HH + ju0);
  lab[t] = labels[b * TT + t];
  if (t < HH) {
    h16[0][t] = (_Float16)0.f; h16[1][t] = (_Float16)0.f;
    E16[0][t] = (_Float16)0.f; E16[1][t] = (_Float16)0.f;
  }
  if (t < 16) redE[t >> 3][t & 7] = 0.f;
  if (t < 2) pre0[t] = 0.f;

  const float* pcb = precomp + (size_t)b * TT * G4;
  float4 nxt[4];
#pragma unroll
  for (int g = 0; g < 4; ++g)
    nxt[g] = *(const float4*)(pcb + g * 128 + ju0);

  f32x4 cst = {0.f, 0.f, 0.f, 0.f};
  f32x4 pre = {0.f, 0.f, 0.f, 0.f};
  f32x4 e_prev = {1.f, 1.f, 1.f, 1.f};
  float mused = 0.f, emit = 0.f;
  __syncthreads();

#pragma unroll 1
  for (int n = 0; n <= TT; ++n) {
    // ---- LDS reads of prev-iteration state (RAW across exactly 1 barrier) -
    f16x8 Bh[4], Be[4];
    if (n < TT) {
      const _Float16* hb = &h16[(n + 1) & 1][0];  // h(n-1)
#pragma unroll
      for (int kc = 0; kc < 4; ++kc)
        Bh[kc] = *(const f16x8*)(hb + kc * 32 + quad * 8);
    }
    if (n > 0) {
      const _Float16* eb = &E16[n & 1][0];        // E(n-2)
#pragma unroll
      for (int kc = 0; kc < 4; ++kc)
        Be[kc] = *(const f16x8*)(eb + kc * 32 + quad * 8);
    }
    const float4 rA = *(const float4*)&redE[(n + 1) & 1][0];  // tot(n-1)
    const float4 rB = *(const float4*)&redE[(n + 1) & 1][4];
    float Mnew = pre0[(n + 1) & 1];                           // pre(n-2)[0]
    const int labn = lab[(n > 0 ? n : 1) - 1];

    f32x4 e_cur = e_prev;
    if (n < TT) {
      f32x4 acc[4];
#pragma unroll
      for (int g = 0; g < 4; ++g) acc[g] = __builtin_bit_cast(f32x4, nxt[g]);
#pragma unroll
      for (int kc = 0; kc < 4; ++kc)
#pragma unroll
        for (int g = 0; g < 4; ++g)
          acc[g] = __builtin_amdgcn_mfma_f32_16x16x32_f16(Al[g][kc], Bh[kc], acc[g], 0, 0, 0);
      if (n + 1 < TT) {
        const float* p2 = pcb + (size_t)(n + 1) * G4;
#pragma unroll
        for (int g = 0; g < 4; ++g)
          nxt[g] = *(const float4*)(p2 + g * 128 + ju0);
      }
      f32x4 hv;
#pragma unroll
      for (int r = 0; r < 4; ++r) {
        const float iv = sigmoid_(acc[0][r]), fv = sigmoid_(acc[1][r]);
        const float gv = tanh_(acc[2][r]), ov = sigmoid_(acc[3][r]);
        cst[r] = fv * cst[r] + iv * gv;
        hv[r] = ov * tanh_(cst[r]);
        e_cur[r] = __expf(hv[r]);  // |hv|<1
      }
      float ts = wr ? (e_cur[0] + e_cur[1] + e_cur[2] + e_cur[3]) : 0.f;
      ts = wave_sum63(ts);  // exact sum over this wave's 16 units
      if (L == 63) redE[n & 1][ww] = ts;
      if (wr) {
        f16x4 hx;
#pragma unroll
        for (int r = 0; r < 4; ++r) hx[r] = (_Float16)hv[r];
        *(f16x4*)&h16[n & 1][ju0] = hx;
      }
    }
    if (n > 0) {
      f32x4 s = {0.f, 0.f, 0.f, 0.f};
#pragma unroll
      for (int kc = 0; kc < 4; ++kc)
        s = __builtin_amdgcn_mfma_f32_16x16x32_f16(Ac[kc], Be[kc], s, 0, 0, 0);
      const float tot = rA.x + rA.y + rA.z + rA.w + rB.x + rB.y + rB.z + rB.w;
      const float rtot = rcp_(tot);
      if (n == 1) Mnew = 0.f;
#pragma unroll
      for (int r = 0; r < 4; ++r) {
        const float p = e_prev[r] * rtot;  // softmax prob of unit ju0+r
        if (n == 1) pre[r] = p + tr0[r];
        else pre[r] = p + mused + __logf(s[r]);
        if (wr && labn == ju0 + r) emit += p;
      }
      if (t == 0) pre0[n & 1] = pre[0];  // t==0 owns unit 0, reg 0
      if (wr) {
        f16x4 Ex;
#pragma unroll
        for (int r = 0; r < 4; ++r) Ex[r] = (_Float16)__expf(pre[r] - Mnew);
        *(f16x4*)&E16[(n + 1) & 1][ju0] = Ex;
      }
      mused = Mnew;
    }
    e_prev = e_cur;
    __syncthreads();
  }

  // ---- epilogue: Ps = LSE_j(pre + trans[127][j]); out_b = Ps - emit -------
  f32x4 v;
  float mx = -1e30f;
#pragma unroll
  for (int r = 0; r < 4; ++r) { v[r] = pre[r] + tr127[r]; mx = fmaxf(mx, v[r]); }
#pragma unroll
  for (int d = 1; d <= 32; d <<= 1) mx = fmaxf(mx, __shfl_xor(mx, d));
  if (L == 0) fin[ww] = mx;
  __syncthreads();
  float M2 = fin[0];
#pragma unroll
  for (int i = 1; i < 8; ++i) M2 = fmaxf(M2, fin[i]);
  float ex = 0.f;
  if (wr) {
#pragma unroll
    for (int r = 0; r < 4; ++r) ex += __expf(v[r] - M2);
  }
  ex = wave_sum63(ex);
  float em = wave_sum63(wr ? emit : 0.f);
  if (L == 63) { fin[8 + ww] = ex; fin[16 + ww] = em; }
  __syncthreads();
  if (t == 0) {
    float S = 0.f, E = 0.f;
#pragma unroll
    for (int i = 0; i < 8; ++i) { S += fin[8 + i]; E += fin[16 + i]; }
    out_b[b] = (M2 + __logf(S)) - E;
  }
}

// ---------------------------------------------------------------------------
// Kernel D: d_out += out_b[b] - sum_t trans[l_t][l_{t+1}]   (one block per b)
// ---------------------------------------------------------------------------
__global__ __launch_bounds__(256) void finalize_kernel(
    const float* __restrict__ trans, const int* __restrict__ labels,
    const float* __restrict__ out_b, float* __restrict__ d_out) {
  const int b = blockIdx.x, t = threadIdx.x;
  float a = 0.f;
  for (int i = t; i < TT - 1; i += 256) {
    const int l0 = labels[b * TT + i];
    const int l1 = labels[b * TT + i + 1];
    a += trans[l0 * HH + l1];
  }
#pragma unroll
  for (int d = 1; d <= 32; d <<= 1) a += __shfl_xor(a, d);
  __shared__ float red[4];
  if ((t & 63) == 0) red[t >> 6] = a;
  __syncthreads();
  if (t == 0) {
    const float tr = red[0] + red[1] + red[2] + red[3];
    atomicAdd(d_out, out_b[b] - tr);
  }
}

// ---------------------------------------------------------------------------
extern "C" void kernel_launch(void* const* d_in, const int* in_sizes, int n_in,
                              void* d_out, int out_size, void* d_ws, size_t ws_size,
                              hipStream_t stream) {
  const float* inputs = (const float*)d_in[0];
  const int* labels = (const int*)d_in[1];
  const float* W_ih = (const float*)d_in[2];
  const float* W_hh = (const float*)d_in[3];
  const float* b_ih = (const float*)d_in[4];
  const float* b_hh = (const float*)d_in[5];
  const float* transition = (const float*)d_in[6];

  char* ws = (char*)d_ws;
  float* precomp = (float*)ws;                              // 64 MiB
  size_t off = 67108864;
  float* trans = (float*)(ws + off); off += 65536;          // 64 KiB
  _Float16* W16 = (_Float16*)(ws + off); off += 262144;     // 256 KiB
  _Float16* Whh16 = (_Float16*)(ws + off); off += 131072;   // 128 KiB
  _Float16* ETT = (_Float16*)(ws + off); off += 32768;      // 32 KiB
  float* out_b = (float*)(ws + off);

  prep_kernel<<<320, 128, 0, stream>>>(transition, W_ih, W_hh, trans, W16, Whh16);
  prep2_kernel<<<64, 256, 0, stream>>>(trans, ETT);
  gemm_in<<<dim3(512, 2), 256, 0, stream>>>(inputs, W16, b_ih, b_hh, precomp);
  lstm_crf<<<64, 512, 0, stream>>>(precomp, Whh16, ETT, trans, labels, out_b);
  (void)hipMemsetAsync(d_out, 0, sizeof(float), stream);
  finalize_kernel<<<64, 256, 0, stream>>>(trans, labels, out_b, (float*)d_out);
}